// Round 6
// baseline (150.807 us; speedup 1.0000x reference)
//
#include <hip/hip_runtime.h>

// B=2, HEADS=8, T=8, QH=QW=16, D=64; rows = 32768, K = 2048.
// out[row, k] = scores[row, k] + dotH(qh,kh) + dotW(qw,kw) + dotT(t,kt)
// k = kt*256 + kh*16 + kw; row = (b*H+n)*2048 + t*256 + qh*16 + qw.
//
// v6: v4 structure with (a) plain cached loads/stores (no nontemporal) and
// (b) the 8 stream loads issued FIRST so they are the oldest entries in the
// VMEM queue; the bias prelude (q/emb loads + dot) executes while they are
// in flight. One wave per row, biases hoisted to registers via own-wave LDS
// (no barrier needed).

#define ROWS 4

typedef float v4f __attribute__((ext_vector_type(4)));

__global__ __launch_bounds__(256, 8) void relpos_fused_v6(
    const float* __restrict__ query,   // [32768, 64]
    const float* __restrict__ scores,  // [32768, 2048]
    const float* __restrict__ hemb,    // [31, 64]
    const float* __restrict__ wemb,    // [31, 64]
    const float* __restrict__ temb,    // [15, 64]
    float* __restrict__ out)           // [32768, 2048]
{
    __shared__ float biasH[ROWS][16];
    __shared__ float biasW[ROWS][16];
    __shared__ float biasT[ROWS][8];

    const int tid  = threadIdx.x;
    const int wv   = tid >> 6;             // wave id = local row
    const int lane = tid & 63;

    const int grow = blockIdx.x * ROWS + wv;  // global row [0, 32768)

    // --- Issue the 8 stream loads FIRST (oldest in VMEM queue) ---
    const v4f* s4p = (const v4f*)scores + (size_t)grow * 512 + lane;
    v4f*       o4p = (v4f*)out          + (size_t)grow * 512 + lane;
    v4f s[8];
    #pragma unroll
    for (int i = 0; i < 8; ++i)
        s[i] = s4p[i * 64];

    // --- Prelude: 40 bias dots for this wave's row (lanes 0..39) ---
    const int row = grow & 2047;
    const int tt  = row >> 8;
    const int qh  = (row >> 4) & 15;
    const int qw  = row & 15;
    if (lane < 40) {
        const float* emb;
        int eidx;
        if (lane < 16)      { emb = hemb; eidx = qh - lane + 15; }
        else if (lane < 32) { emb = wemb; eidx = qw - (lane - 16) + 15; }
        else                { emb = temb; eidx = tt - (lane - 32) + 7; }
        const v4f* e4 = (const v4f*)(emb + eidx * 64);
        const v4f* q4 = (const v4f*)(query + (size_t)grow * 64);
        v4f a4 = (v4f)(0.f);
        #pragma unroll
        for (int k = 0; k < 16; ++k) a4 += q4[k] * e4[k];
        const float acc = (a4.x + a4.y) + (a4.z + a4.w);
        if (lane < 16)      biasH[wv][lane] = acc;
        else if (lane < 32) biasW[wv][lane - 16] = acc;
        else                biasT[wv][lane - 32] = acc;
    }
    // Own-wave LDS write->read: no barrier needed.

    // element = i*256 + lane*4 + c  =>  kt=i, kh=lane>>2, kw quad = lane&3
    const float h  = biasH[wv][lane >> 2];
    const v4f  w4  = ((const v4f*)biasW[wv])[lane & 3];
    const v4f  hw4 = w4 + h;
    float tv[8];
    #pragma unroll
    for (int i = 0; i < 8; ++i) tv[i] = biasT[wv][i];

    // --- Add + store ---
    #pragma unroll
    for (int i = 0; i < 8; ++i) {
        v4f o = s[i] + hw4 + tv[i];
        o4p[i * 64] = o;
    }
}

extern "C" void kernel_launch(void* const* d_in, const int* in_sizes, int n_in,
                              void* d_out, int out_size, void* d_ws, size_t ws_size,
                              hipStream_t stream) {
    const float* query  = (const float*)d_in[0];
    const float* scores = (const float*)d_in[1];
    const float* hemb   = (const float*)d_in[2];
    const float* wemb   = (const float*)d_in[3];
    const float* temb   = (const float*)d_in[4];
    float* out = (float*)d_out;

    relpos_fused_v6<<<32768 / ROWS, 256, 0, stream>>>(
        query, scores, hemb, wemb, temb, out);
}

// Round 7
// 109.601 us; speedup vs baseline: 1.3760x; 1.3760x over previous
//
#include <hip/hip_runtime.h>

// B=2, HEADS=8, T=8, QH=QW=16, D=64; rows = 32768, K = 2048.
// out[row, k] = scores[row, k] + dotH(qh,kh) + dotW(qw,kw) + dotT(t,kt)
// k = kt*256 + kh*16 + kw; row = (b*H+n)*2048 + t*256 + qh*16 + qw.
//
// v7: v4 structure (one wave per row, biases hoisted to registers, no
// barrier) with asymmetric cache policy:
//   - scores loads: PLAIN CACHED -> scores (256 MiB == L3 capacity) may
//     stay L3-resident across graph replays.
//   - out stores: NONTEMPORAL (write-around) -> no write-allocate
//     amplification (v6 showed 1.28x WRITE amplification with cached
//     stores) and no L3 pollution competing with scores.

#define ROWS 4

typedef float v4f __attribute__((ext_vector_type(4)));

__global__ __launch_bounds__(256, 8) void relpos_fused_v7(
    const float* __restrict__ query,   // [32768, 64]
    const float* __restrict__ scores,  // [32768, 2048]
    const float* __restrict__ hemb,    // [31, 64]
    const float* __restrict__ wemb,    // [31, 64]
    const float* __restrict__ temb,    // [15, 64]
    float* __restrict__ out)           // [32768, 2048]
{
    __shared__ float biasH[ROWS][16];
    __shared__ float biasW[ROWS][16];
    __shared__ float biasT[ROWS][8];

    const int tid  = threadIdx.x;
    const int wv   = tid >> 6;             // wave id = local row
    const int lane = tid & 63;

    const int grow = blockIdx.x * ROWS + wv;  // global row [0, 32768)
    const int row  = grow & 2047;             // within (b,n)
    const int tt   = row >> 8;
    const int qh   = (row >> 4) & 15;
    const int qw   = row & 15;

    // --- Prelude: 40 bias dots for this wave's row (lanes 0..39) ---
    if (lane < 40) {
        const float* emb;
        int eidx;
        if (lane < 16)      { emb = hemb; eidx = qh - lane + 15; }
        else if (lane < 32) { emb = wemb; eidx = qw - (lane - 16) + 15; }
        else                { emb = temb; eidx = tt - (lane - 32) + 7; }
        const v4f* e4 = (const v4f*)(emb + eidx * 64);
        const v4f* q4 = (const v4f*)(query + (size_t)grow * 64);
        v4f a4 = (v4f)(0.f);
        #pragma unroll
        for (int k = 0; k < 16; ++k) a4 += q4[k] * e4[k];
        const float acc = (a4.x + a4.y) + (a4.z + a4.w);
        if (lane < 16)      biasH[wv][lane] = acc;
        else if (lane < 32) biasW[wv][lane - 16] = acc;
        else                biasT[wv][lane - 32] = acc;
    }
    // Own-wave LDS write->read: no barrier needed.

    // element = i*256 + lane*4 + c  =>  kt=i, kh=lane>>2, kw quad = lane&3
    const float h  = biasH[wv][lane >> 2];
    const v4f  w4  = ((const v4f*)biasW[wv])[lane & 3];
    const v4f  hw4 = w4 + h;
    float tv[8];
    #pragma unroll
    for (int i = 0; i < 8; ++i) tv[i] = biasT[wv][i];

    // --- Stream: 8 cached loads, then 8 nt stores ---
    const v4f* s4p = (const v4f*)scores + (size_t)grow * 512 + lane;
    v4f*       o4p = (v4f*)out          + (size_t)grow * 512 + lane;

    v4f s[8];
    #pragma unroll
    for (int i = 0; i < 8; ++i)
        s[i] = s4p[i * 64];                      // cached: allow L3 residency
    #pragma unroll
    for (int i = 0; i < 8; ++i) {
        v4f o = s[i] + hw4 + tv[i];
        __builtin_nontemporal_store(o, &o4p[i * 64]);  // write-around
    }
}

extern "C" void kernel_launch(void* const* d_in, const int* in_sizes, int n_in,
                              void* d_out, int out_size, void* d_ws, size_t ws_size,
                              hipStream_t stream) {
    const float* query  = (const float*)d_in[0];
    const float* scores = (const float*)d_in[1];
    const float* hemb   = (const float*)d_in[2];
    const float* wemb   = (const float*)d_in[3];
    const float* temb   = (const float*)d_in[4];
    float* out = (float*)d_out;

    relpos_fused_v7<<<32768 / ROWS, 256, 0, stream>>>(
        query, scores, hemb, wemb, temb, out);
}

// Round 8
// 96.416 us; speedup vs baseline: 1.5641x; 1.1368x over previous
//
#include <hip/hip_runtime.h>

// B=2, HEADS=8, T=8, QH=QW=16, D=64; rows = 32768, K = 2048.
// out[row, k] = scores[row, k] + dotH(qh,kh) + dotW(qw,kw) + dotT(t,kt)
// k = kt*256 + kh*16 + kw; row = (b*H+n)*2048 + t*256 + qh*16 + qw.
//
// v8: v4 (one wave/row, nt load + nt store, reg-hoisted biases, no barrier)
// with a COALESCED bias prelude: 4 groups of 16 lanes; group g computes dots
// d = g*10+j via lane-contiguous emb reads (one 256B emb row per group per
// iter = 2 cache lines) + 4-step shfl_xor butterfly. Replaces the scattered
// 40-lanes x 40-distinct-rows pattern (~640 L1 transactions/row -> ~82).

#define ROWS 4

typedef float v4f __attribute__((ext_vector_type(4)));

__global__ __launch_bounds__(256, 8) void relpos_fused_v8(
    const float* __restrict__ query,   // [32768, 64]
    const float* __restrict__ scores,  // [32768, 2048]
    const float* __restrict__ hemb,    // [31, 64]
    const float* __restrict__ wemb,    // [31, 64]
    const float* __restrict__ temb,    // [15, 64]
    float* __restrict__ out)           // [32768, 2048]
{
    // bias_all[wv][0..15]=H, [16..31]=W, [32..39]=T; 48 floats keeps rows
    // 16B-aligned for the v4f read of the W block.
    __shared__ __align__(16) float bias_all[ROWS][48];

    const int tid  = threadIdx.x;
    const int wv   = tid >> 6;             // wave id = local row
    const int lane = tid & 63;

    const int grow = blockIdx.x * ROWS + wv;  // global row [0, 32768)
    const int row  = grow & 2047;             // within (b,n)
    const int tt   = row >> 8;
    const int qh   = (row >> 4) & 15;
    const int qw   = row & 15;

    // --- Coalesced prelude: 4 groups x 10 dots, butterfly over 16 lanes ---
    const int g = lane >> 4;   // group 0..3
    const int i = lane & 15;   // position within group

    const v4f q4 = ((const v4f*)(query + (size_t)grow * 64))[i];

    #pragma unroll
    for (int j = 0; j < 10; ++j) {
        const int d = g * 10 + j;          // dot index 0..39
        const float* erow;
        if (d < 16)      erow = hemb + (qh - d + 15) * 64;
        else if (d < 32) erow = wemb + (qw - (d - 16) + 15) * 64;
        else             erow = temb + (tt - (d - 32) + 7) * 64;
        const v4f e4 = ((const v4f*)erow)[i];
        const v4f p4 = q4 * e4;
        float p = (p4.x + p4.y) + (p4.z + p4.w);
        p += __shfl_xor(p, 1, 64);
        p += __shfl_xor(p, 2, 64);
        p += __shfl_xor(p, 4, 64);
        p += __shfl_xor(p, 8, 64);
        if (i == 0) bias_all[wv][d] = p;
    }
    // Own-wave LDS write->read: no barrier needed.

    // element = i*256 + lane*4 + c  =>  kt=i, kh=lane>>2, kw quad = lane&3
    const float h  = bias_all[wv][lane >> 2];
    const v4f  w4 = ((const v4f*)(&bias_all[wv][16]))[lane & 3];
    const v4f  hw4 = w4 + h;
    float tv[8];
    #pragma unroll
    for (int k = 0; k < 8; ++k) tv[k] = bias_all[wv][32 + k];

    // --- Pure-VMEM stream: 8 nt loads, then 8 add + nt stores ---
    const v4f* s4p = (const v4f*)scores + (size_t)grow * 512 + lane;
    v4f*       o4p = (v4f*)out          + (size_t)grow * 512 + lane;

    v4f s[8];
    #pragma unroll
    for (int k = 0; k < 8; ++k)
        s[k] = __builtin_nontemporal_load(&s4p[k * 64]);
    #pragma unroll
    for (int k = 0; k < 8; ++k) {
        v4f o = s[k] + hw4 + tv[k];
        __builtin_nontemporal_store(o, &o4p[k * 64]);
    }
}

extern "C" void kernel_launch(void* const* d_in, const int* in_sizes, int n_in,
                              void* d_out, int out_size, void* d_ws, size_t ws_size,
                              hipStream_t stream) {
    const float* query  = (const float*)d_in[0];
    const float* scores = (const float*)d_in[1];
    const float* hemb   = (const float*)d_in[2];
    const float* wemb   = (const float*)d_in[3];
    const float* temb   = (const float*)d_in[4];
    float* out = (float*)d_out;

    relpos_fused_v8<<<32768 / ROWS, 256, 0, stream>>>(
        query, scores, hemb, wemb, temb, out);
}